// Round 20
// baseline (197.901 us; speedup 1.0000x reference)
//
#include <hip/hip_runtime.h>
#include <math.h>

#define S_LEN  1024
#define DMODEL 1024
#define DH     64

typedef float  f4     __attribute__((ext_vector_type(4)));
typedef float  f32x4  __attribute__((ext_vector_type(4)));
typedef __bf16 bf16x2 __attribute__((ext_vector_type(2)));
typedef __bf16 bf16x4 __attribute__((ext_vector_type(4)));
typedef __bf16 bf16x8 __attribute__((ext_vector_type(8)));
typedef unsigned int u32x4 __attribute__((ext_vector_type(4)));

__device__ __forceinline__ bf16x8 neg8(bf16x8 v) {
    u32x4 u;
    __builtin_memcpy(&u, &v, 16);
    u ^= 0x80008000u;
    bf16x8 r;
    __builtin_memcpy(&r, &u, 16);
    return r;
}

// 16B global -> LDS DMA (gfx950). LDS dest is wave-uniform base + lane*16.
__device__ __forceinline__ void gload16(const __bf16* g, __bf16* l) {
    __builtin_amdgcn_global_load_lds(
        (const __attribute__((address_space(1))) void*)g,
        (__attribute__((address_space(3))) void*)l,
        16, 0, 0);
}

// ---------------------------------------------------------------------------
// Fused split kernel. x -> 2 PLAIN bf16 planes (re,im — lo dropped, unused);
// weights -> 4 hi/lo planes.
// ---------------------------------------------------------------------------
__global__ __launch_bounds__(256)
void split_all(const float* __restrict__ xre, const float* __restrict__ xim,
               const float* __restrict__ wqre, const float* __restrict__ wqim,
               const float* __restrict__ wkre, const float* __restrict__ wkim,
               const float* __restrict__ wvre, const float* __restrict__ wvim,
               const float* __restrict__ wore, const float* __restrict__ woim,
               __bf16* __restrict__ xs, __bf16* __restrict__ wqkvs,
               __bf16* __restrict__ wos)
{
    const size_t P1M = (size_t)1024 * 1024;
    const size_t P2M = 2 * P1M;
    const size_t P3M = 3 * P1M;
    const int bid = blockIdx.x;
    const float* re; const float* im; __bf16* dst; size_t plane; int idx;
    bool xcase = false;
    if (bid < 1024)      { re = xre;  im = xim;  dst = xs;            plane = P2M; idx = bid*256; xcase = true; }
    else if (bid < 1536) { re = wqre; im = wqim; dst = wqkvs;         plane = P3M; idx = (bid-1024)*256; }
    else if (bid < 2048) { re = wkre; im = wkim; dst = wqkvs + P1M;   plane = P3M; idx = (bid-1536)*256; }
    else if (bid < 2560) { re = wvre; im = wvim; dst = wqkvs + 2*P1M; plane = P3M; idx = (bid-2048)*256; }
    else                 { re = wore; im = woim; dst = wos;           plane = P1M; idx = (bid-2560)*256; }
    idx += threadIdx.x;

    f4 r0 = ((const f4*)re)[idx*2];
    f4 r1 = ((const f4*)re)[idx*2+1];
    f4 i0 = ((const f4*)im)[idx*2];
    f4 i1 = ((const f4*)im)[idx*2+1];
    float rr[8] = {r0.x,r0.y,r0.z,r0.w,r1.x,r1.y,r1.z,r1.w};
    float ii[8] = {i0.x,i0.y,i0.z,i0.w,i1.x,i1.y,i1.z,i1.w};
    bf16x8 hr, lr, hi, li;
    #pragma unroll
    for (int j = 0; j < 8; ++j) {
        __bf16 h = (__bf16)rr[j];
        hr[j] = h; lr[j] = (__bf16)(rr[j] - (float)h);
        __bf16 g = (__bf16)ii[j];
        hi[j] = g; li[j] = (__bf16)(ii[j] - (float)g);
    }
    if (xcase) {
        ((bf16x8*)(dst + 0*plane))[idx] = hr;
        ((bf16x8*)(dst + 1*plane))[idx] = hi;
    } else {
        ((bf16x8*)(dst + 0*plane))[idx] = hr;
        ((bf16x8*)(dst + 1*plane))[idx] = lr;
        ((bf16x8*)(dst + 2*plane))[idx] = hi;
        ((bf16x8*)(dst + 3*plane))[idx] = li;
    }
}

// ---------------------------------------------------------------------------
// QKV GEMM (round-19 structure): A = plain-bf16 x (2 planes, stride P2M).
//   seg 0 (Q): 8-pass, scale 1/8, RoPE -> plain bf16 (2 planes)
//   seg 1 (K): 8-pass, RoPE -> plain bf16 (2 planes)
//   seg 2 (V): 4-pass hh-only -> direct transposed bf16 Vt store
// ---------------------------------------------------------------------------
__global__ __launch_bounds__(256, 2)
void cgemm_qkv(const __bf16* __restrict__ A, const __bf16* __restrict__ B,
               __bf16* __restrict__ qp, __bf16* __restrict__ kp,
               __bf16* __restrict__ vt)
{
    __shared__ __bf16 As[2*128*32];
    __shared__ __bf16 Bs[4*64*32];

    const int tid  = threadIdx.x;
    const int lane = tid & 63;
    const int wid  = tid >> 6;
    const int wm   = wid >> 1, wn = wid & 1;
    const int lrow = lane & 15, lk = lane >> 4;
    const int nlin  = blockIdx.x + (blockIdx.y << 4);
    const int xcd   = nlin & 7;
    const int local = nlin >> 3;           // 0..95
    const int m0    = (xcd*2 + (local & 1)) * 128;
    const int n0    = (local >> 1) * 64;
    const int seg   = n0 >> 10;
    const size_t aPlane = (size_t)2048 * 1024;   // x plane stride (2 planes)
    const size_t bPlane = (size_t)3072 * 1024;
    const size_t P2M    = (size_t)2048 * 1024;

    const int laneOff = (lane >> 2) * 1024 + (((lane & 3) ^ ((lane >> 3) & 3)) << 3);

    f32x4 accRe[4][2], accIm[4][2];
    #pragma unroll
    for (int i = 0; i < 4; ++i)
        #pragma unroll
        for (int j = 0; j < 2; ++j) {
            accRe[i][j] = (f32x4){0.f,0.f,0.f,0.f};
            accIm[i][j] = (f32x4){0.f,0.f,0.f,0.f};
        }

    const int phys = (lk ^ ((lrow >> 1) & 3)) << 3;

    for (int it = 0; it < 32; ++it) {
        const int k0 = it * 32;
        __syncthreads();
        if (wid < 2) {
            // wave 0 -> x re; wave 1 -> x im
            const __bf16* ga = A + (size_t)wid*aPlane + (size_t)m0*1024 + k0 + laneOff;
            __bf16* la = &As[(wid*128)*32];
            #pragma unroll
            for (int g2 = 0; g2 < 8; ++g2)
                gload16(ga + (size_t)(g2*16)*1024, la + (g2*16)*32);
        } else {
            // wave 2 -> B planes 0,1; wave 3 -> B planes 2,3
            const __bf16* gb = B + (size_t)((wid-2)*2)*bPlane + (size_t)n0*1024 + k0 + laneOff;
            __bf16* lb = &Bs[((wid-2)*2*64)*32];
            #pragma unroll
            for (int g2 = 0; g2 < 4; ++g2)
                gload16(gb + (size_t)(g2*16)*1024, lb + (g2*16)*32);
            #pragma unroll
            for (int g2 = 0; g2 < 4; ++g2)
                gload16(gb + bPlane + (size_t)(g2*16)*1024, lb + 64*32 + (g2*16)*32);
        }
        __syncthreads();

        bf16x8 bw[2][4];
        #pragma unroll
        for (int nf = 0; nf < 2; ++nf)
            #pragma unroll
            for (int mat = 0; mat < 4; ++mat)
                bw[nf][mat] = *(const bf16x8*)&Bs[(mat*64 + wn*32 + nf*16 + lrow)*32 + phys];
        #pragma unroll
        for (int mf = 0; mf < 4; ++mf) {
            const int arow = wm*64 + mf*16 + lrow;
            bf16x8 xhr = *(const bf16x8*)&As[(0*128 + arow)*32 + phys];
            bf16x8 xhi = *(const bf16x8*)&As[(1*128 + arow)*32 + phys];
            bf16x8 nhi = neg8(xhi);
            if (seg == 2) {
                #pragma unroll
                for (int nf = 0; nf < 2; ++nf) {
                    f32x4 r  = accRe[mf][nf];
                    f32x4 m2 = accIm[mf][nf];
                    r  = __builtin_amdgcn_mfma_f32_16x16x32_bf16(xhr, bw[nf][0], r, 0,0,0);
                    r  = __builtin_amdgcn_mfma_f32_16x16x32_bf16(nhi, bw[nf][2], r, 0,0,0);
                    m2 = __builtin_amdgcn_mfma_f32_16x16x32_bf16(xhr, bw[nf][2], m2, 0,0,0);
                    m2 = __builtin_amdgcn_mfma_f32_16x16x32_bf16(xhi, bw[nf][0], m2, 0,0,0);
                    accRe[mf][nf] = r; accIm[mf][nf] = m2;
                }
            } else {
                #pragma unroll
                for (int nf = 0; nf < 2; ++nf) {
                    f32x4 r  = accRe[mf][nf];
                    f32x4 m2 = accIm[mf][nf];
                    r  = __builtin_amdgcn_mfma_f32_16x16x32_bf16(xhr, bw[nf][0], r, 0,0,0);
                    r  = __builtin_amdgcn_mfma_f32_16x16x32_bf16(xhr, bw[nf][1], r, 0,0,0);
                    r  = __builtin_amdgcn_mfma_f32_16x16x32_bf16(nhi, bw[nf][2], r, 0,0,0);
                    r  = __builtin_amdgcn_mfma_f32_16x16x32_bf16(nhi, bw[nf][3], r, 0,0,0);
                    m2 = __builtin_amdgcn_mfma_f32_16x16x32_bf16(xhr, bw[nf][2], m2, 0,0,0);
                    m2 = __builtin_amdgcn_mfma_f32_16x16x32_bf16(xhr, bw[nf][3], m2, 0,0,0);
                    m2 = __builtin_amdgcn_mfma_f32_16x16x32_bf16(xhi, bw[nf][0], m2, 0,0,0);
                    m2 = __builtin_amdgcn_mfma_f32_16x16x32_bf16(xhi, bw[nf][1], m2, 0,0,0);
                    accRe[mf][nf] = r; accIm[mf][nf] = m2;
                }
            }
        }
    }

    const int nloc = n0 & 1023;
    #pragma unroll
    for (int mf = 0; mf < 4; ++mf) {
        #pragma unroll
        for (int nf = 0; nf < 2; ++nf) {
            const int colB = wn*32 + nf*16 + lrow;   // 0..63 == dh
            f32x4 r  = accRe[mf][nf];
            f32x4 m2 = accIm[mf][nf];
            if (seg == 2) {
                const int sBase = m0 + wm*64 + mf*16 + lk*4;
                const int b     = m0 >> 10;
                const int h     = nloc >> 6;
                const int sloc  = sBase & 1023;
                bf16x4 vr, vi;
                #pragma unroll
                for (int rg = 0; rg < 4; ++rg) { vr[rg] = (__bf16)r[rg]; vi[rg] = (__bf16)m2[rg]; }
                size_t off = (size_t)((b*16 + h)*64 + colB) * 1024 + sloc;
                *(bf16x4*)(vt + off)       = vr;
                *(bf16x4*)(vt + P2M + off) = vi;
                continue;
            }
            const float invf = __expf(-(float)colB * 0.14391157f); // ln(1e4)/64
            #pragma unroll
            for (int rg = 0; rg < 4; ++rg) {
                const int m = m0 + wm*64 + mf*16 + lk*4 + rg;
                float re = r[rg], im = m2[rg];
                if (seg == 0) { re *= 0.125f; im *= 0.125f; }
                float sn, cs;
                __sincosf((float)(m & (S_LEN-1)) * invf, &sn, &cs);
                float t = re*cs - im*sn;
                im = re*sn + im*cs; re = t;
                __bf16* dp = (seg == 0) ? qp : kp;
                size_t off = (size_t)m*1024 + nloc + colB;
                dp[off]       = (__bf16)re;
                dp[P2M + off] = (__bf16)im;
            }
        }
    }
}

// ---------------------------------------------------------------------------
// O projection, 8-pass (unchanged): plain-bf16 O x split wo.
// ---------------------------------------------------------------------------
__global__ __launch_bounds__(256, 2)
void cgemm_o(const __bf16* __restrict__ A, const __bf16* __restrict__ B,
             float* __restrict__ outI)
{
    __shared__ __bf16 As[2*128*32];
    __shared__ __bf16 Bs[4*64*32];

    const int tid  = threadIdx.x;
    const int lane = tid & 63;
    const int wid  = tid >> 6;
    const int wm   = wid >> 1, wn = wid & 1;
    const int lrow = lane & 15, lk = lane >> 4;
    const int nlin  = blockIdx.x + (blockIdx.y << 4);
    const int xcd   = nlin & 7;
    const int local = nlin >> 3;           // 0..31
    const int m0    = (xcd*2 + (local & 1)) * 128;
    const int n0    = (local >> 1) * 64;
    const size_t aPlane = (size_t)2048 * 1024;
    const size_t bPlane = (size_t)1024 * 1024;

    f32x4 accRe[4][2], accIm[4][2];
    #pragma unroll
    for (int i = 0; i < 4; ++i)
        #pragma unroll
        for (int j = 0; j < 2; ++j) {
            accRe[i][j] = (f32x4){0.f,0.f,0.f,0.f};
            accIm[i][j] = (f32x4){0.f,0.f,0.f,0.f};
        }

    f4 prA[4], prB[4];
    #pragma unroll
    for (int i = 0; i < 4; ++i) {
        int c = tid + 256*i;                 // 0..1023
        int mat = c >> 9, row = (c >> 2) & 127, ks = c & 3;
        prA[i] = *(const f4*)(A + (size_t)mat*aPlane + (size_t)(m0+row)*1024 + ks*8);
    }
    #pragma unroll
    for (int i = 0; i < 4; ++i) {
        int c = tid + 256*i;
        int mat = c >> 8, row = (c >> 2) & 63, ks = c & 3;
        prB[i] = *(const f4*)(B + (size_t)mat*bPlane + (size_t)(n0+row)*1024 + ks*8);
    }

    const int phys = (lk ^ ((lrow >> 1) & 3)) << 3;

    for (int it = 0; it < 32; ++it) {
        __syncthreads();
        #pragma unroll
        for (int i = 0; i < 4; ++i) {
            int c = tid + 256*i;
            int mat = c >> 9, row = (c >> 2) & 127, ks = c & 3;
            int wp = (ks ^ ((row >> 1) & 3)) << 3;
            *(f4*)&As[(mat*128 + row)*32 + wp] = prA[i];
        }
        #pragma unroll
        for (int i = 0; i < 4; ++i) {
            int c = tid + 256*i;
            int mat = c >> 8, row = (c >> 2) & 63, ks = c & 3;
            int wp = (ks ^ ((row >> 1) & 3)) << 3;
            *(f4*)&Bs[(mat*64 + row)*32 + wp] = prB[i];
        }
        __syncthreads();
        if (it < 31) {
            const int k0 = (it + 1) * 32;
            #pragma unroll
            for (int i = 0; i < 4; ++i) {
                int c = tid + 256*i;
                int mat = c >> 9, row = (c >> 2) & 127, ks = c & 3;
                prA[i] = *(const f4*)(A + (size_t)mat*aPlane + (size_t)(m0+row)*1024 + k0 + ks*8);
            }
            #pragma unroll
            for (int i = 0; i < 4; ++i) {
                int c = tid + 256*i;
                int mat = c >> 8, row = (c >> 2) & 63, ks = c & 3;
                prB[i] = *(const f4*)(B + (size_t)mat*bPlane + (size_t)(n0+row)*1024 + k0 + ks*8);
            }
        }
        bf16x8 bw[2][4];
        #pragma unroll
        for (int nf = 0; nf < 2; ++nf)
            #pragma unroll
            for (int mat = 0; mat < 4; ++mat)
                bw[nf][mat] = *(const bf16x8*)&Bs[(mat*64 + wn*32 + nf*16 + lrow)*32 + phys];
        #pragma unroll
        for (int mf = 0; mf < 4; ++mf) {
            const int arow = wm*64 + mf*16 + lrow;
            bf16x8 xor_ = *(const bf16x8*)&As[(0*128 + arow)*32 + phys];
            bf16x8 xoi  = *(const bf16x8*)&As[(1*128 + arow)*32 + phys];
            bf16x8 noi  = neg8(xoi);
            #pragma unroll
            for (int nf = 0; nf < 2; ++nf) {
                f32x4 r  = accRe[mf][nf];
                f32x4 m2 = accIm[mf][nf];
                r  = __builtin_amdgcn_mfma_f32_16x16x32_bf16(xor_, bw[nf][0], r, 0,0,0);
                r  = __builtin_amdgcn_mfma_f32_16x16x32_bf16(xor_, bw[nf][1], r, 0,0,0);
                r  = __builtin_amdgcn_mfma_f32_16x16x32_bf16(noi,  bw[nf][2], r, 0,0,0);
                r  = __builtin_amdgcn_mfma_f32_16x16x32_bf16(noi,  bw[nf][3], r, 0,0,0);
                m2 = __builtin_amdgcn_mfma_f32_16x16x32_bf16(xor_, bw[nf][2], m2, 0,0,0);
                m2 = __builtin_amdgcn_mfma_f32_16x16x32_bf16(xor_, bw[nf][3], m2, 0,0,0);
                m2 = __builtin_amdgcn_mfma_f32_16x16x32_bf16(xoi,  bw[nf][0], m2, 0,0,0);
                m2 = __builtin_amdgcn_mfma_f32_16x16x32_bf16(xoi,  bw[nf][1], m2, 0,0,0);
                accRe[mf][nf] = r; accIm[mf][nf] = m2;
            }
        }
    }

    #pragma unroll
    for (int mf = 0; mf < 4; ++mf) {
        #pragma unroll
        for (int nf = 0; nf < 2; ++nf) {
            const int colB = wn*32 + nf*16 + lrow;
            f32x4 r  = accRe[mf][nf];
            f32x4 m2 = accIm[mf][nf];
            #pragma unroll
            for (int rg = 0; rg < 4; ++rg) {
                const int m = m0 + wm*64 + mf*16 + lk*4 + rg;
                size_t off = ((size_t)m*1024 + n0 + colB)*2;
                outI[off] = r[rg]; outI[off+1] = m2[rg];
            }
        }
    }
}

// ---------------------------------------------------------------------------
// MFMA flash attention, v7: KVBLK=64 (16 iters, half the barrier rounds).
// Key permutation: key k -> phys ((k&1)<<5)|(k>>1); thread lq's scores are
// keys {2lq, 2lq+1, 32+2lq, 33+2lq} -> two aligned bf16x2 P-writes per row.
// Fixed-offset softmax, XCD swizzle, plain-bf16 Q/K/O.
// ---------------------------------------------------------------------------
__global__ __launch_bounds__(128, 2)
void flash_mfma(const __bf16* __restrict__ Qp, const __bf16* __restrict__ Kp,
                const __bf16* __restrict__ Vt, __bf16* __restrict__ Os)
{
    __shared__ __align__(16) __bf16 Ks[2][64][72];   // [plane][permuted key][dh]
    __shared__ __align__(16) __bf16 Vs[2][64][72];   // [plane][d][key] natural
    __shared__ __align__(16) __bf16 Pa[2][16][72];   // per-wave P real (key order)
    __shared__ __align__(16) __bf16 Pb[2][16][72];   // per-wave P imag

    const int tid  = threadIdx.x;
    const int lane = tid & 63;
    const int w    = tid >> 6;
    const int lq   = lane & 15;
    const int g    = lane >> 4;       // 0..3
    const int nlin  = blockIdx.x + (blockIdx.y << 5);
    const int xcd   = nlin & 7;
    const int local = nlin >> 3;           // 0..127
    const int bh    = xcd*4 + (local & 3);
    const int q0    = (local >> 2) * 32;
    const int b     = bh >> 4, h = bh & 15;
    const size_t P2M = (size_t)2048 * 1024;

    bf16x8 qf[2][2];
    {
        const size_t qrow = (size_t)(b*1024 + q0 + w*16 + lq) * 1024 + h*64;
        #pragma unroll
        for (int p = 0; p < 2; ++p)
            #pragma unroll
            for (int kc = 0; kc < 2; ++kc)
                qf[p][kc] = *(const bf16x8*)(Qp + (size_t)p*P2M + qrow + kc*32 + g*8);
    }

    f32x4 oRe[4], oIm[4];
    #pragma unroll
    for (int d = 0; d < 4; ++d) { oRe[d] = (f32x4){0,0,0,0}; oIm[d] = (f32x4){0,0,0,0}; }
    float lsum[4] = {0.f, 0.f, 0.f, 0.f};

    bf16x8 pk[8]; bf16x8 pv[8];
    #pragma unroll
    for (int i = 0; i < 8; ++i) {
        int c = tid + 128*i;                 // 0..1023
        int p = c >> 9, key = (c >> 3) & 63, cc = c & 7;
        pk[i] = *(const bf16x8*)(Kp + (size_t)p*P2M + (size_t)(b*1024 + key)*1024 + h*64 + cc*8);
    }
    #pragma unroll
    for (int i = 0; i < 8; ++i) {
        int c = tid + 128*i;
        int p = c >> 9, d = (c >> 3) & 63, cc = c & 7;
        pv[i] = *(const bf16x8*)(Vt + (size_t)p*P2M + (size_t)(bh*64 + d)*1024 + cc*8);
    }

    for (int it = 0; it < 16; ++it) {
        __syncthreads();
        #pragma unroll
        for (int i = 0; i < 8; ++i) {
            int c = tid + 128*i;
            int p = c >> 9, key = (c >> 3) & 63, cc = c & 7;
            int pr = ((key & 1) << 5) | (key >> 1);   // permuted row
            *(bf16x8*)&Ks[p][pr][cc*8] = pk[i];
        }
        #pragma unroll
        for (int i = 0; i < 8; ++i) {
            int c = tid + 128*i;
            int p = c >> 9, d = (c >> 3) & 63, cc = c & 7;
            *(bf16x8*)&Vs[p][d][cc*8] = pv[i];
        }
        if (it < 15) {
            const int t0 = (it + 1) * 64;
            #pragma unroll
            for (int i = 0; i < 8; ++i) {
                int c = tid + 128*i;
                int p = c >> 9, key = (c >> 3) & 63, cc = c & 7;
                pk[i] = *(const bf16x8*)(Kp + (size_t)p*P2M + (size_t)(b*1024 + t0 + key)*1024 + h*64 + cc*8);
            }
            #pragma unroll
            for (int i = 0; i < 8; ++i) {
                int c = tid + 128*i;
                int p = c >> 9, d = (c >> 3) & 63, cc = c & 7;
                pv[i] = *(const bf16x8*)(Vt + (size_t)p*P2M + (size_t)(bh*64 + d)*1024 + t0 + cc*8);
            }
        }
        __syncthreads();

        // QK^H: phys row f*16+lq: f=0 -> key 2lq, f=1 -> 32+2lq,
        //                         f=2 -> 2lq+1, f=3 -> 33+2lq
        f32x4 sRe[4], sIm[4];
        #pragma unroll
        for (int f = 0; f < 4; ++f) { sRe[f] = (f32x4){0,0,0,0}; sIm[f] = (f32x4){0,0,0,0}; }
        __builtin_amdgcn_s_setprio(1);
        #pragma unroll
        for (int kc = 0; kc < 2; ++kc) {
            #pragma unroll
            for (int f = 0; f < 4; ++f) {
                const int prow = f*16 + lq;
                bf16x8 kr = *(const bf16x8*)&Ks[0][prow][kc*32 + g*8];
                bf16x8 ki = *(const bf16x8*)&Ks[1][prow][kc*32 + g*8];
                bf16x8 nki = neg8(ki);
                f32x4 r = sRe[f], m2 = sIm[f];
                r  = __builtin_amdgcn_mfma_f32_16x16x32_bf16(qf[0][kc], kr,  r, 0,0,0);
                r  = __builtin_amdgcn_mfma_f32_16x16x32_bf16(qf[1][kc], ki,  r, 0,0,0);
                m2 = __builtin_amdgcn_mfma_f32_16x16x32_bf16(qf[1][kc], kr,  m2, 0,0,0);
                m2 = __builtin_amdgcn_mfma_f32_16x16x32_bf16(qf[0][kc], nki, m2, 0,0,0);
                sRe[f] = r; sIm[f] = m2;
            }
        }
        __builtin_amdgcn_s_setprio(0);

        // fixed-offset softmax: P = exp(s - 8); two bf16x2 writes per row
        #pragma unroll
        for (int i = 0; i < 4; ++i) {
            float p0 = __expf(sRe[0][i] - 8.f);   // key 2lq
            float p1 = __expf(sRe[2][i] - 8.f);   // key 2lq+1
            float p2 = __expf(sRe[1][i] - 8.f);   // key 32+2lq
            float p3 = __expf(sRe[3][i] - 8.f);   // key 33+2lq
            lsum[i] += (p0 + p1) + (p2 + p3);
            float sn0, cs0, sn1, cs1, sn2, cs2, sn3, cs3;
            __sincosf(sIm[0][i], &sn0, &cs0);
            __sincosf(sIm[2][i], &sn1, &cs1);
            __sincosf(sIm[1][i], &sn2, &cs2);
            __sincosf(sIm[3][i], &sn3, &cs3);
            const int row = g*4 + i;
            ((bf16x2*)&Pa[w][row][0])[lq]  = (bf16x2){(__bf16)(p0*cs0), (__bf16)(p1*cs1)};
            ((bf16x2*)&Pb[w][row][0])[lq]  = (bf16x2){(__bf16)(p0*sn0), (__bf16)(p1*sn1)};
            ((bf16x2*)&Pa[w][row][32])[lq] = (bf16x2){(__bf16)(p2*cs2), (__bf16)(p3*cs3)};
            ((bf16x2*)&Pb[w][row][32])[lq] = (bf16x2){(__bf16)(p2*sn2), (__bf16)(p3*sn3)};
        }

        // PV over 64 keys (two 32-key chunks), P cols and Vs rows natural
        __builtin_amdgcn_s_setprio(1);
        #pragma unroll
        for (int kc2 = 0; kc2 < 2; ++kc2) {
            bf16x8 pa  = *(const bf16x8*)&Pa[w][lq][kc2*32 + g*8];
            bf16x8 pb  = *(const bf16x8*)&Pb[w][lq][kc2*32 + g*8];
            bf16x8 npb = neg8(pb);
            #pragma unroll
            for (int df = 0; df < 4; ++df) {
                bf16x8 vr = *(const bf16x8*)&Vs[0][df*16 + lq][kc2*32 + g*8];
                bf16x8 vi = *(const bf16x8*)&Vs[1][df*16 + lq][kc2*32 + g*8];
                oRe[df] = __builtin_amdgcn_mfma_f32_16x16x32_bf16(pa,  vr, oRe[df], 0,0,0);
                oRe[df] = __builtin_amdgcn_mfma_f32_16x16x32_bf16(npb, vi, oRe[df], 0,0,0);
                oIm[df] = __builtin_amdgcn_mfma_f32_16x16x32_bf16(pa,  vi, oIm[df], 0,0,0);
                oIm[df] = __builtin_amdgcn_mfma_f32_16x16x32_bf16(pb,  vr, oIm[df], 0,0,0);
            }
        }
        __builtin_amdgcn_s_setprio(0);
    }

    // one final reduce of lsum across the 16-lane key groups
    #pragma unroll
    for (int i = 0; i < 4; ++i) {
        #pragma unroll
        for (int mm = 1; mm < 16; mm <<= 1)
            lsum[i] += __shfl_xor(lsum[i], mm, 16);
    }

    // normalize + store plain bf16 O (2 planes)
    #pragma unroll
    for (int i = 0; i < 4; ++i) {
        const float inv = 1.f / lsum[i];
        const size_t rowOff = (size_t)(b*1024 + q0 + w*16 + g*4 + i) * 1024 + h*64;
        #pragma unroll
        for (int df = 0; df < 4; ++df) {
            size_t off = rowOff + df*16 + lq;
            Os[off]       = (__bf16)(oRe[df][i] * inv);
            Os[P2M + off] = (__bf16)(oIm[df][i] * inv);
        }
    }
}

// ---------------------------------------------------------------------------
extern "C" void kernel_launch(void* const* d_in, const int* in_sizes, int n_in,
                              void* d_out, int out_size, void* d_ws, size_t ws_size,
                              hipStream_t stream)
{
    (void)in_sizes; (void)n_in; (void)out_size; (void)ws_size;
    const float* x_re  = (const float*)d_in[0];
    const float* x_im  = (const float*)d_in[1];
    const float* wq_re = (const float*)d_in[2];
    const float* wq_im = (const float*)d_in[3];
    const float* wk_re = (const float*)d_in[4];
    const float* wk_im = (const float*)d_in[5];
    const float* wv_re = (const float*)d_in[6];
    const float* wv_im = (const float*)d_in[7];
    const float* wo_re = (const float*)d_in[8];
    const float* wo_im = (const float*)d_in[9];
    float* out = (float*)d_out;

    char* wsb = (char*)d_ws;
    const size_t MB = (size_t)1 << 20;
    __bf16* x_s    = (__bf16*)(wsb +  0*MB);   // 2 planes (8MB); dead after QKV
    __bf16* Os_g   = (__bf16*)(wsb +  0*MB);   // 2 planes (8MB)
    __bf16* wqkv_s = (__bf16*)(wsb + 16*MB);
    __bf16* wo_s   = (__bf16*)(wsb + 40*MB);
    __bf16* Qs_g   = (__bf16*)(wsb + 48*MB);   // 2 planes (8MB)
    __bf16* Ks_g   = (__bf16*)(wsb + 64*MB);   // 2 planes (8MB)
    __bf16* Vt_g   = (__bf16*)(wsb + 80*MB);

    // fused split: x -> 2 plain-bf16 planes; weights -> 4 hi/lo planes
    split_all<<<3072, 256, 0, stream>>>(x_re, x_im, wq_re, wq_im, wk_re, wk_im,
                                        wv_re, wv_im, wo_re, wo_im,
                                        x_s, wqkv_s, wo_s);
    // fused QKV projection (8-pass Q/K, 4-pass V; plain-bf16 x)
    cgemm_qkv<<<dim3(16, 48), 256, 0, stream>>>(x_s, wqkv_s, Qs_g, Ks_g, Vt_g);
    // MFMA flash attention (KVBLK=64) -> bf16 O planes
    flash_mfma<<<dim3(32, 32), 128, 0, stream>>>(Qs_g, Ks_g, Vt_g, Os_g);
    // O projection (8-pass), interleaved (re,im) store
    cgemm_o<<<dim3(16, 16), 256, 0, stream>>>(Os_g, wo_s, out);
}

// Round 21
// 181.886 us; speedup vs baseline: 1.0881x; 1.0881x over previous
//
#include <hip/hip_runtime.h>
#include <math.h>

#define S_LEN  1024
#define DMODEL 1024
#define DH     64

typedef float  f4     __attribute__((ext_vector_type(4)));
typedef float  f32x4  __attribute__((ext_vector_type(4)));
typedef __bf16 bf16x2 __attribute__((ext_vector_type(2)));
typedef __bf16 bf16x4 __attribute__((ext_vector_type(4)));
typedef __bf16 bf16x8 __attribute__((ext_vector_type(8)));
typedef unsigned int u32x4 __attribute__((ext_vector_type(4)));

__device__ __forceinline__ bf16x8 neg8(bf16x8 v) {
    u32x4 u;
    __builtin_memcpy(&u, &v, 16);
    u ^= 0x80008000u;
    bf16x8 r;
    __builtin_memcpy(&r, &u, 16);
    return r;
}

// 16B global -> LDS DMA (gfx950). LDS dest is wave-uniform base + lane*16.
__device__ __forceinline__ void gload16(const __bf16* g, __bf16* l) {
    __builtin_amdgcn_global_load_lds(
        (const __attribute__((address_space(1))) void*)g,
        (__attribute__((address_space(3))) void*)l,
        16, 0, 0);
}

// ---------------------------------------------------------------------------
// Fused split kernel. x -> 2 PLAIN bf16 planes (re,im); weights -> 4 planes.
// ---------------------------------------------------------------------------
__global__ __launch_bounds__(256)
void split_all(const float* __restrict__ xre, const float* __restrict__ xim,
               const float* __restrict__ wqre, const float* __restrict__ wqim,
               const float* __restrict__ wkre, const float* __restrict__ wkim,
               const float* __restrict__ wvre, const float* __restrict__ wvim,
               const float* __restrict__ wore, const float* __restrict__ woim,
               __bf16* __restrict__ xs, __bf16* __restrict__ wqkvs,
               __bf16* __restrict__ wos)
{
    const size_t P1M = (size_t)1024 * 1024;
    const size_t P2M = 2 * P1M;
    const size_t P3M = 3 * P1M;
    const int bid = blockIdx.x;
    const float* re; const float* im; __bf16* dst; size_t plane; int idx;
    bool xcase = false;
    if (bid < 1024)      { re = xre;  im = xim;  dst = xs;            plane = P2M; idx = bid*256; xcase = true; }
    else if (bid < 1536) { re = wqre; im = wqim; dst = wqkvs;         plane = P3M; idx = (bid-1024)*256; }
    else if (bid < 2048) { re = wkre; im = wkim; dst = wqkvs + P1M;   plane = P3M; idx = (bid-1536)*256; }
    else if (bid < 2560) { re = wvre; im = wvim; dst = wqkvs + 2*P1M; plane = P3M; idx = (bid-2048)*256; }
    else                 { re = wore; im = woim; dst = wos;           plane = P1M; idx = (bid-2560)*256; }
    idx += threadIdx.x;

    f4 r0 = ((const f4*)re)[idx*2];
    f4 r1 = ((const f4*)re)[idx*2+1];
    f4 i0 = ((const f4*)im)[idx*2];
    f4 i1 = ((const f4*)im)[idx*2+1];
    float rr[8] = {r0.x,r0.y,r0.z,r0.w,r1.x,r1.y,r1.z,r1.w};
    float ii[8] = {i0.x,i0.y,i0.z,i0.w,i1.x,i1.y,i1.z,i1.w};
    bf16x8 hr, lr, hi, li;
    #pragma unroll
    for (int j = 0; j < 8; ++j) {
        __bf16 h = (__bf16)rr[j];
        hr[j] = h; lr[j] = (__bf16)(rr[j] - (float)h);
        __bf16 g = (__bf16)ii[j];
        hi[j] = g; li[j] = (__bf16)(ii[j] - (float)g);
    }
    if (xcase) {
        ((bf16x8*)(dst + 0*plane))[idx] = hr;
        ((bf16x8*)(dst + 1*plane))[idx] = hi;
    } else {
        ((bf16x8*)(dst + 0*plane))[idx] = hr;
        ((bf16x8*)(dst + 1*plane))[idx] = lr;
        ((bf16x8*)(dst + 2*plane))[idx] = hi;
        ((bf16x8*)(dst + 3*plane))[idx] = li;
    }
}

// ---------------------------------------------------------------------------
// QKV GEMM (round-20 version, unchanged — measured 79.5 µs):
// A = plain-bf16 x (2 planes). seg 0/1: 8-pass + RoPE -> plain bf16;
// seg 2: 4-pass hh-only -> direct Vt. DMA staging + XCD swizzle.
// ---------------------------------------------------------------------------
__global__ __launch_bounds__(256, 2)
void cgemm_qkv(const __bf16* __restrict__ A, const __bf16* __restrict__ B,
               __bf16* __restrict__ qp, __bf16* __restrict__ kp,
               __bf16* __restrict__ vt)
{
    __shared__ __bf16 As[2*128*32];
    __shared__ __bf16 Bs[4*64*32];

    const int tid  = threadIdx.x;
    const int lane = tid & 63;
    const int wid  = tid >> 6;
    const int wm   = wid >> 1, wn = wid & 1;
    const int lrow = lane & 15, lk = lane >> 4;
    const int nlin  = blockIdx.x + (blockIdx.y << 4);
    const int xcd   = nlin & 7;
    const int local = nlin >> 3;           // 0..95
    const int m0    = (xcd*2 + (local & 1)) * 128;
    const int n0    = (local >> 1) * 64;
    const int seg   = n0 >> 10;
    const size_t aPlane = (size_t)2048 * 1024;
    const size_t bPlane = (size_t)3072 * 1024;
    const size_t P2M    = (size_t)2048 * 1024;

    const int laneOff = (lane >> 2) * 1024 + (((lane & 3) ^ ((lane >> 3) & 3)) << 3);

    f32x4 accRe[4][2], accIm[4][2];
    #pragma unroll
    for (int i = 0; i < 4; ++i)
        #pragma unroll
        for (int j = 0; j < 2; ++j) {
            accRe[i][j] = (f32x4){0.f,0.f,0.f,0.f};
            accIm[i][j] = (f32x4){0.f,0.f,0.f,0.f};
        }

    const int phys = (lk ^ ((lrow >> 1) & 3)) << 3;

    for (int it = 0; it < 32; ++it) {
        const int k0 = it * 32;
        __syncthreads();
        if (wid < 2) {
            const __bf16* ga = A + (size_t)wid*aPlane + (size_t)m0*1024 + k0 + laneOff;
            __bf16* la = &As[(wid*128)*32];
            #pragma unroll
            for (int g2 = 0; g2 < 8; ++g2)
                gload16(ga + (size_t)(g2*16)*1024, la + (g2*16)*32);
        } else {
            const __bf16* gb = B + (size_t)((wid-2)*2)*bPlane + (size_t)n0*1024 + k0 + laneOff;
            __bf16* lb = &Bs[((wid-2)*2*64)*32];
            #pragma unroll
            for (int g2 = 0; g2 < 4; ++g2)
                gload16(gb + (size_t)(g2*16)*1024, lb + (g2*16)*32);
            #pragma unroll
            for (int g2 = 0; g2 < 4; ++g2)
                gload16(gb + bPlane + (size_t)(g2*16)*1024, lb + 64*32 + (g2*16)*32);
        }
        __syncthreads();

        bf16x8 bw[2][4];
        #pragma unroll
        for (int nf = 0; nf < 2; ++nf)
            #pragma unroll
            for (int mat = 0; mat < 4; ++mat)
                bw[nf][mat] = *(const bf16x8*)&Bs[(mat*64 + wn*32 + nf*16 + lrow)*32 + phys];
        #pragma unroll
        for (int mf = 0; mf < 4; ++mf) {
            const int arow = wm*64 + mf*16 + lrow;
            bf16x8 xhr = *(const bf16x8*)&As[(0*128 + arow)*32 + phys];
            bf16x8 xhi = *(const bf16x8*)&As[(1*128 + arow)*32 + phys];
            bf16x8 nhi = neg8(xhi);
            if (seg == 2) {
                #pragma unroll
                for (int nf = 0; nf < 2; ++nf) {
                    f32x4 r  = accRe[mf][nf];
                    f32x4 m2 = accIm[mf][nf];
                    r  = __builtin_amdgcn_mfma_f32_16x16x32_bf16(xhr, bw[nf][0], r, 0,0,0);
                    r  = __builtin_amdgcn_mfma_f32_16x16x32_bf16(nhi, bw[nf][2], r, 0,0,0);
                    m2 = __builtin_amdgcn_mfma_f32_16x16x32_bf16(xhr, bw[nf][2], m2, 0,0,0);
                    m2 = __builtin_amdgcn_mfma_f32_16x16x32_bf16(xhi, bw[nf][0], m2, 0,0,0);
                    accRe[mf][nf] = r; accIm[mf][nf] = m2;
                }
            } else {
                #pragma unroll
                for (int nf = 0; nf < 2; ++nf) {
                    f32x4 r  = accRe[mf][nf];
                    f32x4 m2 = accIm[mf][nf];
                    r  = __builtin_amdgcn_mfma_f32_16x16x32_bf16(xhr, bw[nf][0], r, 0,0,0);
                    r  = __builtin_amdgcn_mfma_f32_16x16x32_bf16(xhr, bw[nf][1], r, 0,0,0);
                    r  = __builtin_amdgcn_mfma_f32_16x16x32_bf16(nhi, bw[nf][2], r, 0,0,0);
                    r  = __builtin_amdgcn_mfma_f32_16x16x32_bf16(nhi, bw[nf][3], r, 0,0,0);
                    m2 = __builtin_amdgcn_mfma_f32_16x16x32_bf16(xhr, bw[nf][2], m2, 0,0,0);
                    m2 = __builtin_amdgcn_mfma_f32_16x16x32_bf16(xhr, bw[nf][3], m2, 0,0,0);
                    m2 = __builtin_amdgcn_mfma_f32_16x16x32_bf16(xhi, bw[nf][0], m2, 0,0,0);
                    m2 = __builtin_amdgcn_mfma_f32_16x16x32_bf16(xhi, bw[nf][1], m2, 0,0,0);
                    accRe[mf][nf] = r; accIm[mf][nf] = m2;
                }
            }
        }
    }

    const int nloc = n0 & 1023;
    #pragma unroll
    for (int mf = 0; mf < 4; ++mf) {
        #pragma unroll
        for (int nf = 0; nf < 2; ++nf) {
            const int colB = wn*32 + nf*16 + lrow;   // 0..63 == dh
            f32x4 r  = accRe[mf][nf];
            f32x4 m2 = accIm[mf][nf];
            if (seg == 2) {
                const int sBase = m0 + wm*64 + mf*16 + lk*4;
                const int b     = m0 >> 10;
                const int h     = nloc >> 6;
                const int sloc  = sBase & 1023;
                bf16x4 vr, vi;
                #pragma unroll
                for (int rg = 0; rg < 4; ++rg) { vr[rg] = (__bf16)r[rg]; vi[rg] = (__bf16)m2[rg]; }
                size_t off = (size_t)((b*16 + h)*64 + colB) * 1024 + sloc;
                *(bf16x4*)(vt + off)       = vr;
                *(bf16x4*)(vt + P2M + off) = vi;
                continue;
            }
            const float invf = __expf(-(float)colB * 0.14391157f); // ln(1e4)/64
            #pragma unroll
            for (int rg = 0; rg < 4; ++rg) {
                const int m = m0 + wm*64 + mf*16 + lk*4 + rg;
                float re = r[rg], im = m2[rg];
                if (seg == 0) { re *= 0.125f; im *= 0.125f; }
                float sn, cs;
                __sincosf((float)(m & (S_LEN-1)) * invf, &sn, &cs);
                float t = re*cs - im*sn;
                im = re*sn + im*cs; re = t;
                __bf16* dp = (seg == 0) ? qp : kp;
                size_t off = (size_t)m*1024 + nloc + colB;
                dp[off]       = (__bf16)re;
                dp[P2M + off] = (__bf16)im;
            }
        }
    }
}

// ---------------------------------------------------------------------------
// O projection, 8-pass (unchanged): plain-bf16 O x split wo.
// ---------------------------------------------------------------------------
__global__ __launch_bounds__(256, 2)
void cgemm_o(const __bf16* __restrict__ A, const __bf16* __restrict__ B,
             float* __restrict__ outI)
{
    __shared__ __bf16 As[2*128*32];
    __shared__ __bf16 Bs[4*64*32];

    const int tid  = threadIdx.x;
    const int lane = tid & 63;
    const int wid  = tid >> 6;
    const int wm   = wid >> 1, wn = wid & 1;
    const int lrow = lane & 15, lk = lane >> 4;
    const int nlin  = blockIdx.x + (blockIdx.y << 4);
    const int xcd   = nlin & 7;
    const int local = nlin >> 3;           // 0..31
    const int m0    = (xcd*2 + (local & 1)) * 128;
    const int n0    = (local >> 1) * 64;
    const size_t aPlane = (size_t)2048 * 1024;
    const size_t bPlane = (size_t)1024 * 1024;

    f32x4 accRe[4][2], accIm[4][2];
    #pragma unroll
    for (int i = 0; i < 4; ++i)
        #pragma unroll
        for (int j = 0; j < 2; ++j) {
            accRe[i][j] = (f32x4){0.f,0.f,0.f,0.f};
            accIm[i][j] = (f32x4){0.f,0.f,0.f,0.f};
        }

    f4 prA[4], prB[4];
    #pragma unroll
    for (int i = 0; i < 4; ++i) {
        int c = tid + 256*i;                 // 0..1023
        int mat = c >> 9, row = (c >> 2) & 127, ks = c & 3;
        prA[i] = *(const f4*)(A + (size_t)mat*aPlane + (size_t)(m0+row)*1024 + ks*8);
    }
    #pragma unroll
    for (int i = 0; i < 4; ++i) {
        int c = tid + 256*i;
        int mat = c >> 8, row = (c >> 2) & 63, ks = c & 3;
        prB[i] = *(const f4*)(B + (size_t)mat*bPlane + (size_t)(n0+row)*1024 + ks*8);
    }

    const int phys = (lk ^ ((lrow >> 1) & 3)) << 3;

    for (int it = 0; it < 32; ++it) {
        __syncthreads();
        #pragma unroll
        for (int i = 0; i < 4; ++i) {
            int c = tid + 256*i;
            int mat = c >> 9, row = (c >> 2) & 127, ks = c & 3;
            int wp = (ks ^ ((row >> 1) & 3)) << 3;
            *(f4*)&As[(mat*128 + row)*32 + wp] = prA[i];
        }
        #pragma unroll
        for (int i = 0; i < 4; ++i) {
            int c = tid + 256*i;
            int mat = c >> 8, row = (c >> 2) & 63, ks = c & 3;
            int wp = (ks ^ ((row >> 1) & 3)) << 3;
            *(f4*)&Bs[(mat*64 + row)*32 + wp] = prB[i];
        }
        __syncthreads();
        if (it < 31) {
            const int k0 = (it + 1) * 32;
            #pragma unroll
            for (int i = 0; i < 4; ++i) {
                int c = tid + 256*i;
                int mat = c >> 9, row = (c >> 2) & 127, ks = c & 3;
                prA[i] = *(const f4*)(A + (size_t)mat*aPlane + (size_t)(m0+row)*1024 + k0 + ks*8);
            }
            #pragma unroll
            for (int i = 0; i < 4; ++i) {
                int c = tid + 256*i;
                int mat = c >> 8, row = (c >> 2) & 63, ks = c & 3;
                prB[i] = *(const f4*)(B + (size_t)mat*bPlane + (size_t)(n0+row)*1024 + k0 + ks*8);
            }
        }
        bf16x8 bw[2][4];
        #pragma unroll
        for (int nf = 0; nf < 2; ++nf)
            #pragma unroll
            for (int mat = 0; mat < 4; ++mat)
                bw[nf][mat] = *(const bf16x8*)&Bs[(mat*64 + wn*32 + nf*16 + lrow)*32 + phys];
        #pragma unroll
        for (int mf = 0; mf < 4; ++mf) {
            const int arow = wm*64 + mf*16 + lrow;
            bf16x8 xor_ = *(const bf16x8*)&As[(0*128 + arow)*32 + phys];
            bf16x8 xoi  = *(const bf16x8*)&As[(1*128 + arow)*32 + phys];
            bf16x8 noi  = neg8(xoi);
            #pragma unroll
            for (int nf = 0; nf < 2; ++nf) {
                f32x4 r  = accRe[mf][nf];
                f32x4 m2 = accIm[mf][nf];
                r  = __builtin_amdgcn_mfma_f32_16x16x32_bf16(xor_, bw[nf][0], r, 0,0,0);
                r  = __builtin_amdgcn_mfma_f32_16x16x32_bf16(xor_, bw[nf][1], r, 0,0,0);
                r  = __builtin_amdgcn_mfma_f32_16x16x32_bf16(noi,  bw[nf][2], r, 0,0,0);
                r  = __builtin_amdgcn_mfma_f32_16x16x32_bf16(noi,  bw[nf][3], r, 0,0,0);
                m2 = __builtin_amdgcn_mfma_f32_16x16x32_bf16(xor_, bw[nf][2], m2, 0,0,0);
                m2 = __builtin_amdgcn_mfma_f32_16x16x32_bf16(xor_, bw[nf][3], m2, 0,0,0);
                m2 = __builtin_amdgcn_mfma_f32_16x16x32_bf16(xoi,  bw[nf][0], m2, 0,0,0);
                m2 = __builtin_amdgcn_mfma_f32_16x16x32_bf16(xoi,  bw[nf][1], m2, 0,0,0);
                accRe[mf][nf] = r; accIm[mf][nf] = m2;
            }
        }
    }

    #pragma unroll
    for (int mf = 0; mf < 4; ++mf) {
        #pragma unroll
        for (int nf = 0; nf < 2; ++nf) {
            const int colB = wn*32 + nf*16 + lrow;
            f32x4 r  = accRe[mf][nf];
            f32x4 m2 = accIm[mf][nf];
            #pragma unroll
            for (int rg = 0; rg < 4; ++rg) {
                const int m = m0 + wm*64 + mf*16 + lk*4 + rg;
                size_t off = ((size_t)m*1024 + n0 + colB)*2;
                outI[off] = r[rg]; outI[off+1] = m2[rg];
            }
        }
    }
}

// ---------------------------------------------------------------------------
// MFMA flash attention (round-19 version, KVBLK=32 — the measured optimum):
// plain-bf16 Q/K, 4-MFMA complex QK, fixed-offset softmax, XCD swizzle.
// ---------------------------------------------------------------------------
__global__ __launch_bounds__(128, 2)
void flash_mfma(const __bf16* __restrict__ Qp, const __bf16* __restrict__ Kp,
                const __bf16* __restrict__ Vt, __bf16* __restrict__ Os)
{
    __shared__ __align__(16) __bf16 Ks[2][32][72];   // [plane][permuted key][dh]
    __shared__ __align__(16) __bf16 Vs[2][64][40];   // [plane][d][key] natural
    __shared__ __align__(16) __bf16 Pa[2][16][40];   // per-wave P real (key order)
    __shared__ __align__(16) __bf16 Pb[2][16][40];   // per-wave P imag

    const int tid  = threadIdx.x;
    const int lane = tid & 63;
    const int w    = tid >> 6;
    const int lq   = lane & 15;
    const int g    = lane >> 4;       // 0..3
    const int nlin  = blockIdx.x + (blockIdx.y << 5);
    const int xcd   = nlin & 7;
    const int local = nlin >> 3;           // 0..127
    const int bh    = xcd*4 + (local & 3);
    const int q0    = (local >> 2) * 32;
    const int b     = bh >> 4, h = bh & 15;
    const size_t P2M = (size_t)2048 * 1024;

    bf16x8 qf[2][2];
    {
        const size_t qrow = (size_t)(b*1024 + q0 + w*16 + lq) * 1024 + h*64;
        #pragma unroll
        for (int p = 0; p < 2; ++p)
            #pragma unroll
            for (int kc = 0; kc < 2; ++kc)
                qf[p][kc] = *(const bf16x8*)(Qp + (size_t)p*P2M + qrow + kc*32 + g*8);
    }

    f32x4 oRe[4], oIm[4];
    #pragma unroll
    for (int d = 0; d < 4; ++d) { oRe[d] = (f32x4){0,0,0,0}; oIm[d] = (f32x4){0,0,0,0}; }
    float lsum[4] = {0.f, 0.f, 0.f, 0.f};

    bf16x8 pk[4]; bf16x8 pv[4];
    #pragma unroll
    for (int i = 0; i < 4; ++i) {
        int c = tid + 128*i;                 // 0..511
        int p = c >> 8, key = (c >> 3) & 31, cc = c & 7;
        pk[i] = *(const bf16x8*)(Kp + (size_t)p*P2M + (size_t)(b*1024 + key)*1024 + h*64 + cc*8);
    }
    #pragma unroll
    for (int i = 0; i < 4; ++i) {
        int c = tid + 128*i;
        int p = c >> 8, d = (c >> 2) & 63, cc = c & 3;
        pv[i] = *(const bf16x8*)(Vt + (size_t)p*P2M + (size_t)(bh*64 + d)*1024 + cc*8);
    }

    for (int it = 0; it < 32; ++it) {
        __syncthreads();
        #pragma unroll
        for (int i = 0; i < 4; ++i) {
            int c = tid + 128*i;
            int p = c >> 8, key = (c >> 3) & 31, cc = c & 7;
            int pr = ((key & 1) << 4) | (key >> 1);   // permuted row
            *(bf16x8*)&Ks[p][pr][cc*8] = pk[i];
        }
        #pragma unroll
        for (int i = 0; i < 4; ++i) {
            int c = tid + 128*i;
            int p = c >> 8, d = (c >> 2) & 63, cc = c & 3;
            *(bf16x8*)&Vs[p][d][cc*8] = pv[i];
        }
        if (it < 31) {
            const int t0 = (it + 1) * 32;
            #pragma unroll
            for (int i = 0; i < 4; ++i) {
                int c = tid + 128*i;
                int p = c >> 8, key = (c >> 3) & 31, cc = c & 7;
                pk[i] = *(const bf16x8*)(Kp + (size_t)p*P2M + (size_t)(b*1024 + t0 + key)*1024 + h*64 + cc*8);
            }
            #pragma unroll
            for (int i = 0; i < 4; ++i) {
                int c = tid + 128*i;
                int p = c >> 8, d = (c >> 2) & 63, cc = c & 3;
                pv[i] = *(const bf16x8*)(Vt + (size_t)p*P2M + (size_t)(bh*64 + d)*1024 + t0 + cc*8);
            }
        }
        __syncthreads();

        // QK^H (4 MFMA per frag-pair): phys row f*16+lq holds key 2lq+f
        f32x4 sRe[2], sIm[2];
        #pragma unroll
        for (int f = 0; f < 2; ++f) { sRe[f] = (f32x4){0,0,0,0}; sIm[f] = (f32x4){0,0,0,0}; }
        __builtin_amdgcn_s_setprio(1);
        #pragma unroll
        for (int kc = 0; kc < 2; ++kc) {
            #pragma unroll
            for (int f = 0; f < 2; ++f) {
                const int key = f*16 + lq;
                bf16x8 kr = *(const bf16x8*)&Ks[0][key][kc*32 + g*8];
                bf16x8 ki = *(const bf16x8*)&Ks[1][key][kc*32 + g*8];
                bf16x8 nki = neg8(ki);
                f32x4 r = sRe[f], m2 = sIm[f];
                r  = __builtin_amdgcn_mfma_f32_16x16x32_bf16(qf[0][kc], kr,  r, 0,0,0);
                r  = __builtin_amdgcn_mfma_f32_16x16x32_bf16(qf[1][kc], ki,  r, 0,0,0);
                m2 = __builtin_amdgcn_mfma_f32_16x16x32_bf16(qf[1][kc], kr,  m2, 0,0,0);
                m2 = __builtin_amdgcn_mfma_f32_16x16x32_bf16(qf[0][kc], nki, m2, 0,0,0);
                sRe[f] = r; sIm[f] = m2;
            }
        }
        __builtin_amdgcn_s_setprio(0);

        // fixed-offset softmax: P = exp(s - 8), no reductions, no rescale
        #pragma unroll
        for (int i = 0; i < 4; ++i) {
            float p0 = __expf(sRe[0][i] - 8.f);
            float p1 = __expf(sRe[1][i] - 8.f);
            lsum[i] += p0 + p1;
            float sn0, cs0, sn1, cs1;
            __sincosf(sIm[0][i], &sn0, &cs0);
            __sincosf(sIm[1][i], &sn1, &cs1);
            const int row = g*4 + i;
            ((bf16x2*)&Pa[w][row][0])[lq] = (bf16x2){(__bf16)(p0*cs0), (__bf16)(p1*cs1)};
            ((bf16x2*)&Pb[w][row][0])[lq] = (bf16x2){(__bf16)(p0*sn0), (__bf16)(p1*sn1)};
        }

        // PV: P cols and Vs rows in natural key order
        bf16x8 pa  = *(const bf16x8*)&Pa[w][lq][g*8];
        bf16x8 pb  = *(const bf16x8*)&Pb[w][lq][g*8];
        bf16x8 npb = neg8(pb);
        __builtin_amdgcn_s_setprio(1);
        #pragma unroll
        for (int df = 0; df < 4; ++df) {
            bf16x8 vr = *(const bf16x8*)&Vs[0][df*16 + lq][g*8];
            bf16x8 vi = *(const bf16x8*)&Vs[1][df*16 + lq][g*8];
            oRe[df] = __builtin_amdgcn_mfma_f32_16x16x32_bf16(pa,  vr, oRe[df], 0,0,0);
            oRe[df] = __builtin_amdgcn_mfma_f32_16x16x32_bf16(npb, vi, oRe[df], 0,0,0);
            oIm[df] = __builtin_amdgcn_mfma_f32_16x16x32_bf16(pa,  vi, oIm[df], 0,0,0);
            oIm[df] = __builtin_amdgcn_mfma_f32_16x16x32_bf16(pb,  vr, oIm[df], 0,0,0);
        }
        __builtin_amdgcn_s_setprio(0);
    }

    // one final reduce of lsum across the 16-lane key groups
    #pragma unroll
    for (int i = 0; i < 4; ++i) {
        #pragma unroll
        for (int mm = 1; mm < 16; mm <<= 1)
            lsum[i] += __shfl_xor(lsum[i], mm, 16);
    }

    // normalize + store plain bf16 O (2 planes)
    #pragma unroll
    for (int i = 0; i < 4; ++i) {
        const float inv = 1.f / lsum[i];
        const size_t rowOff = (size_t)(b*1024 + q0 + w*16 + g*4 + i) * 1024 + h*64;
        #pragma unroll
        for (int df = 0; df < 4; ++df) {
            size_t off = rowOff + df*16 + lq;
            Os[off]       = (__bf16)(oRe[df][i] * inv);
            Os[P2M + off] = (__bf16)(oIm[df][i] * inv);
        }
    }
}

// ---------------------------------------------------------------------------
extern "C" void kernel_launch(void* const* d_in, const int* in_sizes, int n_in,
                              void* d_out, int out_size, void* d_ws, size_t ws_size,
                              hipStream_t stream)
{
    (void)in_sizes; (void)n_in; (void)out_size; (void)ws_size;
    const float* x_re  = (const float*)d_in[0];
    const float* x_im  = (const float*)d_in[1];
    const float* wq_re = (const float*)d_in[2];
    const float* wq_im = (const float*)d_in[3];
    const float* wk_re = (const float*)d_in[4];
    const float* wk_im = (const float*)d_in[5];
    const float* wv_re = (const float*)d_in[6];
    const float* wv_im = (const float*)d_in[7];
    const float* wo_re = (const float*)d_in[8];
    const float* wo_im = (const float*)d_in[9];
    float* out = (float*)d_out;

    char* wsb = (char*)d_ws;
    const size_t MB = (size_t)1 << 20;
    __bf16* x_s    = (__bf16*)(wsb +  0*MB);   // 2 planes (8MB); dead after QKV
    __bf16* Os_g   = (__bf16*)(wsb +  0*MB);   // 2 planes (8MB)
    __bf16* wqkv_s = (__bf16*)(wsb + 16*MB);
    __bf16* wo_s   = (__bf16*)(wsb + 40*MB);
    __bf16* Qs_g   = (__bf16*)(wsb + 48*MB);   // 2 planes (8MB)
    __bf16* Ks_g   = (__bf16*)(wsb + 64*MB);   // 2 planes (8MB)
    __bf16* Vt_g   = (__bf16*)(wsb + 80*MB);

    // fused split: x -> 2 plain-bf16 planes; weights -> 4 hi/lo planes
    split_all<<<3072, 256, 0, stream>>>(x_re, x_im, wq_re, wq_im, wk_re, wk_im,
                                        wv_re, wv_im, wo_re, wo_im,
                                        x_s, wqkv_s, wo_s);
    // fused QKV projection (8-pass Q/K, 4-pass V; plain-bf16 x)
    cgemm_qkv<<<dim3(16, 48), 256, 0, stream>>>(x_s, wqkv_s, Qs_g, Ks_g, Vt_g);
    // MFMA flash attention (KVBLK=32) -> bf16 O planes
    flash_mfma<<<dim3(32, 32), 128, 0, stream>>>(Qs_g, Ks_g, Vt_g, Os_g);
    // O projection (8-pass), interleaved (re,im) store
    cgemm_o<<<dim3(16, 16), 256, 0, stream>>>(Os_g, wo_s, out);
}